// Round 17
// baseline (203.838 us; speedup 1.0000x reference)
//
#include <hip/hip_runtime.h>
#include <hip/hip_bf16.h>
#include <stdint.h>

typedef __bf16 bf16_t;
typedef __bf16 bf16x8 __attribute__((ext_vector_type(8)));
typedef __bf16 bf16x4 __attribute__((ext_vector_type(4)));
typedef float f32x4 __attribute__((ext_vector_type(4)));

#define DEV static __device__ __forceinline__

DEV f32x4 mfma16(bf16x8 a, bf16x8 b, f32x4 c) {
  return __builtin_amdgcn_mfma_f32_16x16x32_bf16(a, b, c, 0, 0, 0);
}

// async global->LDS, 16B per lane (GEMMs only).
DEV void gll16(const void* g, void* l) {
  __builtin_amdgcn_global_load_lds(
      (const __attribute__((address_space(1))) uint32_t*)g,
      (__attribute__((address_space(3))) uint32_t*)l, 16, 0, 0);
}

// swizzles for 128B-row LDS tiles (XOR 16B-block idx with row low bits)
DEV int swz128(int row, int c16) {
  return (row << 7) + (((c16 ^ row) & 7) << 4);
}
DEV int swzel128(int row, int col) {
  return (row << 7) + ((((col >> 3) ^ row) & 7) << 4) + ((col & 7) << 1);
}

// ---------------- fused cast fp32 -> bf16 (x, qkv_w, proj_w) ----------------
__global__ void __launch_bounds__(256)
cast_all(const float* __restrict__ x, bf16_t* __restrict__ ox,
         const float* __restrict__ w1, bf16_t* __restrict__ ow1,
         const float* __restrict__ w2, bf16_t* __restrict__ ow2) {
  long i = (long)(blockIdx.x * 256 + threadIdx.x) * 8;
  const float* s; bf16_t* d; long off;
  if (i < 6291456L)      { s = x;  d = ox;  off = i; }
  else if (i < 8060928L) { s = w1; d = ow1; off = i - 6291456L; }
  else if (i < 8650752L) { s = w2; d = ow2; off = i - 8060928L; }
  else return;
  float4 a = *(const float4*)(s + off);
  float4 b = *(const float4*)(s + off + 4);
  bf16x8 v;
  v[0] = (bf16_t)a.x; v[1] = (bf16_t)a.y; v[2] = (bf16_t)a.z; v[3] = (bf16_t)a.w;
  v[4] = (bf16_t)b.x; v[5] = (bf16_t)b.y; v[6] = (bf16_t)b.z; v[7] = (bf16_t)b.w;
  *(bf16x8*)(d + off) = v;
}

// SCALE * log2(e): q pre-scaled so attn uses exp2 directly
#define C1Q 0.1803368801111244f

// ---------------- qkv GEMM with fused per-head LN (2-D grid) ----------------
__global__ void __launch_bounds__(256, 2)
gemm_qkv_ln(const bf16_t* __restrict__ A, const bf16_t* __restrict__ Bw,
            const float* __restrict__ bias,
            const float* __restrict__ qg, const float* __restrict__ qb,
            const float* __restrict__ kg, const float* __restrict__ kb,
            bf16_t* __restrict__ qkv, int M, int N, int K) {
  __shared__ __align__(16) char As[8192];
  __shared__ __align__(16) char Bs[8192];
  const int tid = threadIdx.x;
  const int lane = tid & 63;
  const int wave = tid >> 6;
  const int wr = wave >> 1, wc = wave & 1;
  const int tileM = blockIdx.y << 7;
  const int tileN = blockIdx.x << 7;
  const int lrow = lane & 15, lk = lane >> 4;

  f32x4 acc[4][4];
  f32x4 z = {0.f, 0.f, 0.f, 0.f};
#pragma unroll
  for (int m = 0; m < 4; m++)
#pragma unroll
    for (int n = 0; n < 4; n++) acc[m][n] = z;

  const int srow = wave * 16 + (lane >> 2);
  const int sb = lane & 3;
  const bf16_t* Asrc0 = A + (long)(tileM + srow) * K + sb * 8;
  const bf16_t* Asrc1 = A + (long)(tileM + 64 + srow) * K + sb * 8;
  const bf16_t* Bsrc0 = Bw + (long)(tileN + srow) * K + sb * 8;
  const bf16_t* Bsrc1 = Bw + (long)(tileN + 64 + srow) * K + sb * 8;
  char* Adst = As + wave * 1024;
  char* Bdst = Bs + wave * 1024;

  for (int k0 = 0; k0 < K; k0 += 32) {
    __syncthreads();
    gll16(Asrc0 + k0, Adst);
    gll16(Asrc1 + k0, Adst + 4096);
    gll16(Bsrc0 + k0, Bdst);
    gll16(Bsrc1 + k0, Bdst + 4096);
    __syncthreads();
    bf16x8 af[4], bfr[4];
#pragma unroll
    for (int m = 0; m < 4; m++)
      af[m] = *(const bf16x8*)(As + (wr * 64 + m * 16 + lrow) * 64 + lk * 16);
#pragma unroll
    for (int n = 0; n < 4; n++)
      bfr[n] = *(const bf16x8*)(Bs + (wc * 64 + n * 16 + lrow) * 64 + lk * 16);
#pragma unroll
    for (int m = 0; m < 4; m++)
#pragma unroll
      for (int n = 0; n < 4; n++)
        acc[m][n] = mfma16(af[m], bfr[n], acc[m][n]);
  }

  const int t = tileN / 768;
  const int cbase = tileN + wc * 64;
  float g[4], be[4], bv[4];
#pragma unroll
  for (int n = 0; n < 4; n++) bv[n] = bias[cbase + n * 16 + lrow];
  if (t == 0) {
#pragma unroll
    for (int n = 0; n < 4; n++) {
      int d = n * 16 + lrow;
      g[n] = qg[d] * C1Q; be[n] = qb[d] * C1Q;
    }
  } else if (t == 1) {
#pragma unroll
    for (int n = 0; n < 4; n++) {
      int d = n * 16 + lrow;
      g[n] = kg[d]; be[n] = kb[d];
    }
  }

#pragma unroll
  for (int m = 0; m < 4; m++) {
#pragma unroll
    for (int r = 0; r < 4; r++) {
      float v[4];
#pragma unroll
      for (int n = 0; n < 4; n++) v[n] = acc[m][n][r] + bv[n];
      long row = tileM + wr * 64 + m * 16 + lk * 4 + r;
      bf16_t* dst = qkv + row * 2304 + cbase;
      if (t < 2) {
        float s = v[0] + v[1] + v[2] + v[3];
        float s2 = v[0]*v[0] + v[1]*v[1] + v[2]*v[2] + v[3]*v[3];
#pragma unroll
        for (int ofs = 1; ofs <= 8; ofs <<= 1) {
          s  += __shfl_xor(s, ofs);
          s2 += __shfl_xor(s2, ofs);
        }
        float mu = s * (1.f / 64.f);
        float rstd = rsqrtf(s2 * (1.f / 64.f) - mu * mu + 1e-5f);
#pragma unroll
        for (int n = 0; n < 4; n++)
          dst[n * 16 + lrow] = (bf16_t)((v[n] - mu) * rstd * g[n] + be[n]);
      } else {
#pragma unroll
        for (int n = 0; n < 4; n++)
          dst[n * 16 + lrow] = (bf16_t)v[n];
      }
    }
  }
}

// ---------------- proj GEMM (2-D grid) ----------------
__global__ void __launch_bounds__(256, 2)
gemm_bt(const bf16_t* __restrict__ A, const bf16_t* __restrict__ Bw,
        const float* __restrict__ bias, float* __restrict__ Cout,
        int M, int N, int K) {
  __shared__ __align__(16) char As[8192];
  __shared__ __align__(16) char Bs[8192];
  const int tid = threadIdx.x;
  const int lane = tid & 63;
  const int wave = tid >> 6;
  const int wr = wave >> 1, wc = wave & 1;
  const int tileM = blockIdx.y << 7;
  const int tileN = blockIdx.x << 7;
  const int lrow = lane & 15, lk = lane >> 4;

  f32x4 acc[4][4];
  f32x4 z = {0.f, 0.f, 0.f, 0.f};
#pragma unroll
  for (int m = 0; m < 4; m++)
#pragma unroll
    for (int n = 0; n < 4; n++) acc[m][n] = z;

  const int srow = wave * 16 + (lane >> 2);
  const int sb = lane & 3;
  const bf16_t* Asrc0 = A + (long)(tileM + srow) * K + sb * 8;
  const bf16_t* Asrc1 = A + (long)(tileM + 64 + srow) * K + sb * 8;
  const bf16_t* Bsrc0 = Bw + (long)(tileN + srow) * K + sb * 8;
  const bf16_t* Bsrc1 = Bw + (long)(tileN + 64 + srow) * K + sb * 8;
  char* Adst = As + wave * 1024;
  char* Bdst = Bs + wave * 1024;

  for (int k0 = 0; k0 < K; k0 += 32) {
    __syncthreads();
    gll16(Asrc0 + k0, Adst);
    gll16(Asrc1 + k0, Adst + 4096);
    gll16(Bsrc0 + k0, Bdst);
    gll16(Bsrc1 + k0, Bdst + 4096);
    __syncthreads();
    bf16x8 af[4], bfr[4];
#pragma unroll
    for (int m = 0; m < 4; m++)
      af[m] = *(const bf16x8*)(As + (wr * 64 + m * 16 + lrow) * 64 + lk * 16);
#pragma unroll
    for (int n = 0; n < 4; n++)
      bfr[n] = *(const bf16x8*)(Bs + (wc * 64 + n * 16 + lrow) * 64 + lk * 16);
#pragma unroll
    for (int m = 0; m < 4; m++)
#pragma unroll
      for (int n = 0; n < 4; n++)
        acc[m][n] = mfma16(af[m], bfr[n], acc[m][n]);
  }

  const int rg = lk;
#pragma unroll
  for (int n = 0; n < 4; n++) {
    int col = tileN + wc * 64 + n * 16 + lrow;
    float bv = bias[col];
#pragma unroll
    for (int m = 0; m < 4; m++) {
      long row0 = tileM + wr * 64 + m * 16 + rg * 4;
#pragma unroll
      for (int r = 0; r < 4; r++)
        Cout[(row0 + r) * N + col] = acc[m][n][r] + bv;
    }
  }
}

// ---------------- attention: QBLK=128 retest (de-confounded from R6's store bug) ----------------
// R6's QBLK=128 regression was measured WITH the half-density NT store bug (1.6x
// write amplification, found R8, fixed R9) -- never tested with dense stores.
// This kernel: QBLK=128, 768 blocks (XCD swizzle, 96/XCD), 4 waves x 32 rows,
// reg-staged K/V (R16 pattern), 32KB LDS (Q16+K8+V8, P overlays Q), dense NT
// stores, no-max softmax. Mechanism: halves K-staging + barrier exposure chip-wide,
// doubles MFMA per LDS fragment load.
__global__ void __launch_bounds__(256, 2)
attn_kernel(const bf16_t* __restrict__ qkv, float* __restrict__ attn_out,
            bf16_t* __restrict__ out_heads) {
  const int tid = threadIdx.x;
  const int lane = tid & 63;
  const int wave = tid >> 6;
  const int lb = blockIdx.x;            // 0..767
  const int sid = (lb & 7) * 96 + (lb >> 3);    // bijective XCD-chunk swizzle
  const int qt = sid & 7;               // 8 q-tiles of 128 rows
  const int bh = sid >> 3;              // 96 heads
  const int b = bh / 12, h = bh - b * 12;

  const bf16_t* base = qkv + (long)b * 2359296L + h * 64;
  const bf16_t* Qg = base;
  const bf16_t* Kg = base + 768;
  const bf16_t* Vg = base + 1536;

  __shared__ __align__(16) char QP[16384];  // Q 128x64; pass2: per-wave P (32x64)
  __shared__ __align__(16) char Ks[8192];   // K buffer A
  __shared__ __align__(16) char Vt[8192];   // pass1: K buffer B; pass2: V^T

  const int lrow = lane & 15;
  const int lk = lane >> 4;
  const int w32 = wave * 32;
  const int sr = tid >> 2;      // staging row 0..63
  const int sc = tid & 3;       // staging 16B chunk (and sc+4)

  // prologue: reg-stage Q (two 64-row halves) and K0
  {
#pragma unroll
    for (int q = 0; q < 2; q++) {
      const bf16_t* qp = Qg + (long)(qt * 128 + q * 64 + sr) * 2304 + sc * 8;
      bf16x8 q0 = *(const bf16x8*)(qp);
      bf16x8 q1 = *(const bf16x8*)(qp + 32);
      *(bf16x8*)(QP + swz128(q * 64 + sr, sc)) = q0;
      *(bf16x8*)(QP + swz128(q * 64 + sr, 4 + sc)) = q1;
    }
    const bf16_t* kp = Kg + (long)sr * 2304 + sc * 8;
    bf16x8 k0 = *(const bf16x8*)(kp);
    bf16x8 k1 = *(const bf16x8*)(kp + 32);
    *(bf16x8*)(Ks + swz128(sr, sc)) = k0;
    *(bf16x8*)(Ks + swz128(sr, 4 + sc)) = k1;
  }
  __syncthreads();

  bf16x8 qf[2][2];   // [row-frag][k-half]
#pragma unroll
  for (int rf = 0; rf < 2; rf++)
#pragma unroll
    for (int kk = 0; kk < 2; kk++)
      qf[rf][kk] = *(const bf16x8*)(QP + swz128(w32 + rf * 16 + lrow, kk * 4 + lk));

  auto computeS = [&](const char* Kb, f32x4 sfr[2][4]) {
    f32x4 z = {0.f, 0.f, 0.f, 0.f};
#pragma unroll
    for (int rf = 0; rf < 2; rf++)
#pragma unroll
      for (int f = 0; f < 4; f++) sfr[rf][f] = z;
#pragma unroll
    for (int kk = 0; kk < 2; kk++) {
      bf16x8 kf[4];
#pragma unroll
      for (int f = 0; f < 4; f++)
        kf[f] = *(const bf16x8*)(Kb + swz128(f * 16 + lrow, kk * 4 + lk));
#pragma unroll
      for (int rf = 0; rf < 2; rf++)
#pragma unroll
        for (int f = 0; f < 4; f++)
          sfr[rf][f] = mfma16(qf[rf][kk], kf[f], sfr[rf][f]);
    }
  };

  float l_r[2][4] = {{0.f,0.f,0.f,0.f},{0.f,0.f,0.f,0.f}};

  // -------- pass 1: l = sum(exp2(s)); K double-buffered Ks<->Vt; 1 barrier/iter ----
  for (int kt = 0; kt < 16; kt++) {
    const char* cur = (kt & 1) ? Vt : Ks;
    bf16x8 kr0, kr1;
    if (kt < 15) {
      const bf16_t* kp = Kg + (long)((kt + 1) * 64 + sr) * 2304 + sc * 8;
      kr0 = *(const bf16x8*)(kp);
      kr1 = *(const bf16x8*)(kp + 32);
    }
    f32x4 sfr[2][4];
    computeS(cur, sfr);
#pragma unroll
    for (int rf = 0; rf < 2; rf++)
#pragma unroll
      for (int r = 0; r < 4; r++)
        l_r[rf][r] += exp2f(sfr[rf][0][r]) + exp2f(sfr[rf][1][r]) +
                      exp2f(sfr[rf][2][r]) + exp2f(sfr[rf][3][r]);
    if (kt < 15) {
      char* nxt = (kt & 1) ? Ks : Vt;
      *(bf16x8*)(nxt + swz128(sr, sc)) = kr0;
      *(bf16x8*)(nxt + swz128(sr, 4 + sc)) = kr1;
    }
    __syncthreads();
  }

  float il[2][4];
#pragma unroll
  for (int rf = 0; rf < 2; rf++)
#pragma unroll
    for (int r = 0; r < 4; r++) {
      float l = l_r[rf][r];
#pragma unroll
      for (int ofs = 1; ofs <= 8; ofs <<= 1) l += __shfl_xor(l, ofs);
      il[rf][r] = 1.0f / l;
    }

  f32x4 of[2][4];
  {
    f32x4 z = {0.f, 0.f, 0.f, 0.f};
#pragma unroll
    for (int rf = 0; rf < 2; rf++)
#pragma unroll
      for (int f = 0; f < 4; f++) of[rf][f] = z;
  }
  char* Pw = QP + wave * 4096;   // per-wave 32x64 P tile (qf in regs)
  float* attn_base = attn_out + (long)bh * 1048576 + ((long)(qt * 128) << 10);

  // pass-2 prologue: stage K0 -> Ks and V0^T -> Vt
  const int vk = lane, vdg = wave;
  {
    const bf16_t* kp = Kg + (long)sr * 2304 + sc * 8;
    bf16x8 k0 = *(const bf16x8*)(kp);
    bf16x8 k1 = *(const bf16x8*)(kp + 32);
    const bf16_t* vp = Vg + (long)vk * 2304 + vdg * 16;
    bf16x8 v0 = *(const bf16x8*)(vp);
    bf16x8 v1 = *(const bf16x8*)(vp + 8);
    *(bf16x8*)(Ks + swz128(sr, sc)) = k0;
    *(bf16x8*)(Ks + swz128(sr, 4 + sc)) = k1;
#pragma unroll
    for (int j = 0; j < 8; j++) {
      *(bf16_t*)(Vt + swzel128(vdg * 16 + j, vk)) = v0[j];
      *(bf16_t*)(Vt + swzel128(vdg * 16 + 8 + j, vk)) = v1[j];
    }
  }
  __syncthreads();

  // -------- pass 2: S, P->LDS, PV, dense NT stores; re-stage; 2 barriers/iter ----
  for (int kt = 0; kt < 16; kt++) {
    bf16x8 kr0, kr1, vr0, vr1;
    if (kt < 15) {               // early-issue next K,V loads
      const bf16_t* kp = Kg + (long)((kt + 1) * 64 + sr) * 2304 + sc * 8;
      kr0 = *(const bf16x8*)(kp);
      kr1 = *(const bf16x8*)(kp + 32);
      const bf16_t* vp = Vg + (long)((kt + 1) * 64 + vk) * 2304 + vdg * 16;
      vr0 = *(const bf16x8*)(vp);
      vr1 = *(const bf16x8*)(vp + 8);
    }
    f32x4 sfr[2][4];
    computeS(Ks, sfr);
#pragma unroll
    for (int rf = 0; rf < 2; rf++)
#pragma unroll
      for (int f = 0; f < 4; f++)
#pragma unroll
        for (int r = 0; r < 4; r++) {
          float p = exp2f(sfr[rf][f][r]) * il[rf][r];
          *(bf16_t*)(Pw + swzel128(rf * 16 + lk * 4 + r, f * 16 + lrow)) = (bf16_t)p;
        }
    // PV (own Pw ordered by lgkmcnt; Vt published at prior barrier)
#pragma unroll
    for (int kk = 0; kk < 2; kk++) {
      bf16x8 pf[2];
#pragma unroll
      for (int rf = 0; rf < 2; rf++)
        pf[rf] = *(const bf16x8*)(Pw + swz128(rf * 16 + lrow, kk * 4 + lk));
#pragma unroll
      for (int f = 0; f < 4; f++) {
        bf16x8 vf = *(const bf16x8*)(Vt + swz128(f * 16 + lrow, kk * 4 + lk));
#pragma unroll
        for (int rf = 0; rf < 2; rf++)
          of[rf][f] = mfma16(pf[rf], vf, of[rf][f]);
      }
    }
    // DENSE NT attn stores from own Pw (32 rows x 64 cols)
    float* ab = attn_base + kt * 64;
    {
      const int rsub = lane >> 4;      // 0..3
      const int c8 = lane & 15;        // 16 chunks of 4 cols
      const char* psrc = Pw + (c8 & 1) * 8;
#pragma unroll
      for (int i = 0; i < 8; i++) {
        int rl = i * 4 + rsub;         // 0..31
        bf16x4 pv = *(const bf16x4*)(psrc + swz128(rl, c8 >> 1));
        f32x4 v = {(float)pv[0], (float)pv[1], (float)pv[2], (float)pv[3]};
        __builtin_nontemporal_store(
            v, (f32x4*)(ab + ((long)(w32 + rl) << 10) + c8 * 4));
      }
    }
    __syncthreads();             // all waves done reading Ks, Vt
    if (kt < 15) {               // re-stage next tiles
      *(bf16x8*)(Ks + swz128(sr, sc)) = kr0;
      *(bf16x8*)(Ks + swz128(sr, 4 + sc)) = kr1;
#pragma unroll
      for (int j = 0; j < 8; j++) {
        *(bf16_t*)(Vt + swzel128(vdg * 16 + j, vk)) = vr0[j];
        *(bf16_t*)(Vt + swzel128(vdg * 16 + 8 + j, vk)) = vr1[j];
      }
    }
    __syncthreads();             // publish
  }

  // epilogue: out_heads [B,N,C] bf16
#pragma unroll
  for (int rf = 0; rf < 2; rf++)
#pragma unroll
    for (int f = 0; f < 4; f++)
#pragma unroll
      for (int r = 0; r < 4; r++) {
        int nrow = qt * 128 + w32 + rf * 16 + lk * 4 + r;
        int d = f * 16 + lrow;
        out_heads[((long)b * 1024 + nrow) * 768 + h * 64 + d] = (bf16_t)of[rf][f][r];
      }
}

// ---------------- launcher ----------------
extern "C" void kernel_launch(void* const* d_in, const int* in_sizes, int n_in,
                              void* d_out, int out_size, void* d_ws, size_t ws_size,
                              hipStream_t stream) {
  (void)in_sizes; (void)n_in; (void)out_size; (void)ws_size;
  const float* x       = (const float*)d_in[0];
  const float* qkv_w   = (const float*)d_in[1];
  const float* qkv_b   = (const float*)d_in[2];
  const float* q_gamma = (const float*)d_in[3];
  const float* q_beta  = (const float*)d_in[4];
  const float* k_gamma = (const float*)d_in[5];
  const float* k_beta  = (const float*)d_in[6];
  const float* proj_w  = (const float*)d_in[7];
  const float* proj_b  = (const float*)d_in[8];
  float* out = (float*)d_out;

  char* ws = (char*)d_ws;
  bf16_t* x_bf      = (bf16_t*)(ws);               // 12,582,912 B
  bf16_t* wqkv      = (bf16_t*)(ws + 12582912L);   //  3,538,944 B
  bf16_t* wproj     = (bf16_t*)(ws + 16121856L);   //  1,179,648 B
  bf16_t* qkv       = (bf16_t*)(ws + 17301504L);   // 37,748,736 B
  bf16_t* out_heads = (bf16_t*)(ws + 55050240L);   // 12,582,912 B

  cast_all<<<4224, 256, 0, stream>>>(x, x_bf, qkv_w, wqkv, proj_w, wproj);
  gemm_qkv_ln<<<dim3(18, 64), 256, 0, stream>>>(x_bf, wqkv, qkv_b,
                                                q_gamma, q_beta, k_gamma, k_beta,
                                                qkv, 8192, 2304, 768);
  attn_kernel<<<768, 256, 0, stream>>>(qkv, out + 6291456L, out_heads);
  gemm_bt<<<dim3(6, 64), 256, 0, stream>>>(out_heads, wproj, proj_b, out, 8192, 768, 768);
}

// Round 18
// 196.324 us; speedup vs baseline: 1.0383x; 1.0383x over previous
//
#include <hip/hip_runtime.h>
#include <hip/hip_bf16.h>
#include <stdint.h>

typedef __bf16 bf16_t;
typedef __bf16 bf16x8 __attribute__((ext_vector_type(8)));
typedef __bf16 bf16x4 __attribute__((ext_vector_type(4)));
typedef float f32x4 __attribute__((ext_vector_type(4)));

#define DEV static __device__ __forceinline__

DEV f32x4 mfma16(bf16x8 a, bf16x8 b, f32x4 c) {
  return __builtin_amdgcn_mfma_f32_16x16x32_bf16(a, b, c, 0, 0, 0);
}

// async global->LDS, 16B per lane (GEMMs only).
DEV void gll16(const void* g, void* l) {
  __builtin_amdgcn_global_load_lds(
      (const __attribute__((address_space(1))) uint32_t*)g,
      (__attribute__((address_space(3))) uint32_t*)l, 16, 0, 0);
}

// swizzles for 128B-row LDS tiles (XOR 16B-block idx with row low bits)
DEV int swz128(int row, int c16) {
  return (row << 7) + (((c16 ^ row) & 7) << 4);
}
DEV int swzel128(int row, int col) {
  return (row << 7) + ((((col >> 3) ^ row) & 7) << 4) + ((col & 7) << 1);
}

// ---------------- fused cast fp32 -> bf16 (x, qkv_w, proj_w) ----------------
__global__ void __launch_bounds__(256)
cast_all(const float* __restrict__ x, bf16_t* __restrict__ ox,
         const float* __restrict__ w1, bf16_t* __restrict__ ow1,
         const float* __restrict__ w2, bf16_t* __restrict__ ow2) {
  long i = (long)(blockIdx.x * 256 + threadIdx.x) * 8;
  const float* s; bf16_t* d; long off;
  if (i < 6291456L)      { s = x;  d = ox;  off = i; }
  else if (i < 8060928L) { s = w1; d = ow1; off = i - 6291456L; }
  else if (i < 8650752L) { s = w2; d = ow2; off = i - 8060928L; }
  else return;
  float4 a = *(const float4*)(s + off);
  float4 b = *(const float4*)(s + off + 4);
  bf16x8 v;
  v[0] = (bf16_t)a.x; v[1] = (bf16_t)a.y; v[2] = (bf16_t)a.z; v[3] = (bf16_t)a.w;
  v[4] = (bf16_t)b.x; v[5] = (bf16_t)b.y; v[6] = (bf16_t)b.z; v[7] = (bf16_t)b.w;
  *(bf16x8*)(d + off) = v;
}

// SCALE * log2(e): q pre-scaled so attn uses exp2 directly
#define C1Q 0.1803368801111244f

// ---------------- qkv GEMM with fused per-head LN (2-D grid) ----------------
__global__ void __launch_bounds__(256, 2)
gemm_qkv_ln(const bf16_t* __restrict__ A, const bf16_t* __restrict__ Bw,
            const float* __restrict__ bias,
            const float* __restrict__ qg, const float* __restrict__ qb,
            const float* __restrict__ kg, const float* __restrict__ kb,
            bf16_t* __restrict__ qkv, int M, int N, int K) {
  __shared__ __align__(16) char As[8192];
  __shared__ __align__(16) char Bs[8192];
  const int tid = threadIdx.x;
  const int lane = tid & 63;
  const int wave = tid >> 6;
  const int wr = wave >> 1, wc = wave & 1;
  const int tileM = blockIdx.y << 7;
  const int tileN = blockIdx.x << 7;
  const int lrow = lane & 15, lk = lane >> 4;

  f32x4 acc[4][4];
  f32x4 z = {0.f, 0.f, 0.f, 0.f};
#pragma unroll
  for (int m = 0; m < 4; m++)
#pragma unroll
    for (int n = 0; n < 4; n++) acc[m][n] = z;

  const int srow = wave * 16 + (lane >> 2);
  const int sb = lane & 3;
  const bf16_t* Asrc0 = A + (long)(tileM + srow) * K + sb * 8;
  const bf16_t* Asrc1 = A + (long)(tileM + 64 + srow) * K + sb * 8;
  const bf16_t* Bsrc0 = Bw + (long)(tileN + srow) * K + sb * 8;
  const bf16_t* Bsrc1 = Bw + (long)(tileN + 64 + srow) * K + sb * 8;
  char* Adst = As + wave * 1024;
  char* Bdst = Bs + wave * 1024;

  for (int k0 = 0; k0 < K; k0 += 32) {
    __syncthreads();
    gll16(Asrc0 + k0, Adst);
    gll16(Asrc1 + k0, Adst + 4096);
    gll16(Bsrc0 + k0, Bdst);
    gll16(Bsrc1 + k0, Bdst + 4096);
    __syncthreads();
    bf16x8 af[4], bfr[4];
#pragma unroll
    for (int m = 0; m < 4; m++)
      af[m] = *(const bf16x8*)(As + (wr * 64 + m * 16 + lrow) * 64 + lk * 16);
#pragma unroll
    for (int n = 0; n < 4; n++)
      bfr[n] = *(const bf16x8*)(Bs + (wc * 64 + n * 16 + lrow) * 64 + lk * 16);
#pragma unroll
    for (int m = 0; m < 4; m++)
#pragma unroll
      for (int n = 0; n < 4; n++)
        acc[m][n] = mfma16(af[m], bfr[n], acc[m][n]);
  }

  const int t = tileN / 768;
  const int cbase = tileN + wc * 64;
  float g[4], be[4], bv[4];
#pragma unroll
  for (int n = 0; n < 4; n++) bv[n] = bias[cbase + n * 16 + lrow];
  if (t == 0) {
#pragma unroll
    for (int n = 0; n < 4; n++) {
      int d = n * 16 + lrow;
      g[n] = qg[d] * C1Q; be[n] = qb[d] * C1Q;
    }
  } else if (t == 1) {
#pragma unroll
    for (int n = 0; n < 4; n++) {
      int d = n * 16 + lrow;
      g[n] = kg[d]; be[n] = kb[d];
    }
  }

#pragma unroll
  for (int m = 0; m < 4; m++) {
#pragma unroll
    for (int r = 0; r < 4; r++) {
      float v[4];
#pragma unroll
      for (int n = 0; n < 4; n++) v[n] = acc[m][n][r] + bv[n];
      long row = tileM + wr * 64 + m * 16 + lk * 4 + r;
      bf16_t* dst = qkv + row * 2304 + cbase;
      if (t < 2) {
        float s = v[0] + v[1] + v[2] + v[3];
        float s2 = v[0]*v[0] + v[1]*v[1] + v[2]*v[2] + v[3]*v[3];
#pragma unroll
        for (int ofs = 1; ofs <= 8; ofs <<= 1) {
          s  += __shfl_xor(s, ofs);
          s2 += __shfl_xor(s2, ofs);
        }
        float mu = s * (1.f / 64.f);
        float rstd = rsqrtf(s2 * (1.f / 64.f) - mu * mu + 1e-5f);
#pragma unroll
        for (int n = 0; n < 4; n++)
          dst[n * 16 + lrow] = (bf16_t)((v[n] - mu) * rstd * g[n] + be[n]);
      } else {
#pragma unroll
        for (int n = 0; n < 4; n++)
          dst[n * 16 + lrow] = (bf16_t)v[n];
      }
    }
  }
}

// ---------------- proj GEMM (2-D grid) ----------------
__global__ void __launch_bounds__(256, 2)
gemm_bt(const bf16_t* __restrict__ A, const bf16_t* __restrict__ Bw,
        const float* __restrict__ bias, float* __restrict__ Cout,
        int M, int N, int K) {
  __shared__ __align__(16) char As[8192];
  __shared__ __align__(16) char Bs[8192];
  const int tid = threadIdx.x;
  const int lane = tid & 63;
  const int wave = tid >> 6;
  const int wr = wave >> 1, wc = wave & 1;
  const int tileM = blockIdx.y << 7;
  const int tileN = blockIdx.x << 7;
  const int lrow = lane & 15, lk = lane >> 4;

  f32x4 acc[4][4];
  f32x4 z = {0.f, 0.f, 0.f, 0.f};
#pragma unroll
  for (int m = 0; m < 4; m++)
#pragma unroll
    for (int n = 0; n < 4; n++) acc[m][n] = z;

  const int srow = wave * 16 + (lane >> 2);
  const int sb = lane & 3;
  const bf16_t* Asrc0 = A + (long)(tileM + srow) * K + sb * 8;
  const bf16_t* Asrc1 = A + (long)(tileM + 64 + srow) * K + sb * 8;
  const bf16_t* Bsrc0 = Bw + (long)(tileN + srow) * K + sb * 8;
  const bf16_t* Bsrc1 = Bw + (long)(tileN + 64 + srow) * K + sb * 8;
  char* Adst = As + wave * 1024;
  char* Bdst = Bs + wave * 1024;

  for (int k0 = 0; k0 < K; k0 += 32) {
    __syncthreads();
    gll16(Asrc0 + k0, Adst);
    gll16(Asrc1 + k0, Adst + 4096);
    gll16(Bsrc0 + k0, Bdst);
    gll16(Bsrc1 + k0, Bdst + 4096);
    __syncthreads();
    bf16x8 af[4], bfr[4];
#pragma unroll
    for (int m = 0; m < 4; m++)
      af[m] = *(const bf16x8*)(As + (wr * 64 + m * 16 + lrow) * 64 + lk * 16);
#pragma unroll
    for (int n = 0; n < 4; n++)
      bfr[n] = *(const bf16x8*)(Bs + (wc * 64 + n * 16 + lrow) * 64 + lk * 16);
#pragma unroll
    for (int m = 0; m < 4; m++)
#pragma unroll
      for (int n = 0; n < 4; n++)
        acc[m][n] = mfma16(af[m], bfr[n], acc[m][n]);
  }

  const int rg = lk;
#pragma unroll
  for (int n = 0; n < 4; n++) {
    int col = tileN + wc * 64 + n * 16 + lrow;
    float bv = bias[col];
#pragma unroll
    for (int m = 0; m < 4; m++) {
      long row0 = tileM + wr * 64 + m * 16 + rg * 4;
#pragma unroll
      for (int r = 0; r < 4; r++)
        Cout[(row0 + r) * N + col] = acc[m][n][r] + bv;
    }
  }
}

// ---------------- attention: R16 + pass-2 K/V double-buffer (1 barrier/iter) ----------------
// QBLK=64, no-max softmax (|logit*log2e| <= 11.5), dense NT stores, XCD swizzle,
// reg-staged K/V. R18 change: double-buffer K AND V in pass 2 so the re-stage
// writes target the buffer whose readers finished at the PREVIOUS barrier --
// 2 barriers/iter -> 1 (same invariant pass 1 already uses). LDS 24->40KB
// (cap 4 blocks/CU >= measured ~3 residency, so occupancy unaffected).
__global__ void __launch_bounds__(256, 2)
attn_kernel(const bf16_t* __restrict__ qkv, float* __restrict__ attn_out,
            bf16_t* __restrict__ out_heads) {
  const int tid = threadIdx.x;
  const int lane = tid & 63;
  const int wave = tid >> 6;
  const int lb = blockIdx.x;            // 0..1535
  const int sid = (lb & 7) * 192 + (lb >> 3);   // bijective XCD-chunk swizzle
  const int qt = sid & 15;
  const int bh = sid >> 4;
  const int b = bh / 12, h = bh - b * 12;

  const bf16_t* base = qkv + (long)b * 2359296L + h * 64;
  const bf16_t* Qg = base;
  const bf16_t* Kg = base + 768;
  const bf16_t* Vg = base + 1536;

  __shared__ __align__(16) char Ks[16384];  // 2x 8KB K buffers
  __shared__ __align__(16) char Vt[16384];  // 2x 8KB V^T buffers (pass1: spare K)
  __shared__ __align__(16) char QP[8192];   // prologue: Q; then per-wave P

  const int lrow = lane & 15;
  const int lk = lane >> 4;
  const int sr = tid >> 2;      // staging row 0..63
  const int sc = tid & 3;       // staging 16B chunk (and sc+4)

  // prologue: reg-stage Q and K0 -> Ks[0]
  {
    const bf16_t* qp = Qg + (long)(qt * 64 + sr) * 2304 + sc * 8;
    const bf16_t* kp = Kg + (long)sr * 2304 + sc * 8;
    bf16x8 q0 = *(const bf16x8*)(qp);
    bf16x8 q1 = *(const bf16x8*)(qp + 32);
    bf16x8 k0 = *(const bf16x8*)(kp);
    bf16x8 k1 = *(const bf16x8*)(kp + 32);
    *(bf16x8*)(QP + swz128(sr, sc)) = q0;
    *(bf16x8*)(QP + swz128(sr, 4 + sc)) = q1;
    *(bf16x8*)(Ks + swz128(sr, sc)) = k0;
    *(bf16x8*)(Ks + swz128(sr, 4 + sc)) = k1;
  }
  __syncthreads();

  bf16x8 qf[2];
  qf[0] = *(const bf16x8*)(QP + swz128(wave * 16 + lrow, lk));
  qf[1] = *(const bf16x8*)(QP + swz128(wave * 16 + lrow, 4 + lk));

  auto computeS = [&](const char* Kb, f32x4 sfr[4]) {
    f32x4 z = {0.f, 0.f, 0.f, 0.f};
    sfr[0] = z; sfr[1] = z; sfr[2] = z; sfr[3] = z;
#pragma unroll
    for (int kk = 0; kk < 2; kk++)
#pragma unroll
      for (int f = 0; f < 4; f++) {
        bf16x8 kf = *(const bf16x8*)(Kb + swz128(f * 16 + lrow, kk * 4 + lk));
        sfr[f] = mfma16(qf[kk], kf, sfr[f]);
      }
  };

  float l_r[4] = {0.f, 0.f, 0.f, 0.f};

  // -------- pass 1: l = sum(exp2(s)); K double-buffered in Ks; 1 barrier/iter ----
  for (int kt = 0; kt < 16; kt++) {
    const char* cur = Ks + (kt & 1) * 8192;
    bf16x8 kr0, kr1;
    if (kt < 15) {               // early-issue next K tile loads
      const bf16_t* kp = Kg + (long)((kt + 1) * 64 + sr) * 2304 + sc * 8;
      kr0 = *(const bf16x8*)(kp);
      kr1 = *(const bf16x8*)(kp + 32);
    }
    f32x4 sfr[4];
    computeS(cur, sfr);
#pragma unroll
    for (int r = 0; r < 4; r++)
      l_r[r] += exp2f(sfr[0][r]) + exp2f(sfr[1][r]) +
                exp2f(sfr[2][r]) + exp2f(sfr[3][r]);
    if (kt < 15) {               // write OTHER buffer (readers done at prev barrier)
      char* nxt = Ks + ((kt + 1) & 1) * 8192;
      *(bf16x8*)(nxt + swz128(sr, sc)) = kr0;
      *(bf16x8*)(nxt + swz128(sr, 4 + sc)) = kr1;
    }
    __syncthreads();
  }

  float il[4];
#pragma unroll
  for (int r = 0; r < 4; r++) {
#pragma unroll
    for (int ofs = 1; ofs <= 8; ofs <<= 1)
      l_r[r] += __shfl_xor(l_r[r], ofs);
    il[r] = 1.0f / l_r[r];
  }

  f32x4 of[4];
  {
    f32x4 z = {0.f, 0.f, 0.f, 0.f};
    of[0] = z; of[1] = z; of[2] = z; of[3] = z;
  }
  char* Pw = QP + wave * 2048;
  float* attn_base = attn_out + (long)bh * 1048576 + ((long)(qt * 64) << 10);

  // pass-2 prologue: K0 -> Ks[0], V0^T -> Vt[0]
  const int vk = lane, vdg = wave;
  {
    const bf16_t* kp = Kg + (long)sr * 2304 + sc * 8;
    bf16x8 k0 = *(const bf16x8*)(kp);
    bf16x8 k1 = *(const bf16x8*)(kp + 32);
    const bf16_t* vp = Vg + (long)vk * 2304 + vdg * 16;
    bf16x8 v0 = *(const bf16x8*)(vp);
    bf16x8 v1 = *(const bf16x8*)(vp + 8);
    *(bf16x8*)(Ks + swz128(sr, sc)) = k0;
    *(bf16x8*)(Ks + swz128(sr, 4 + sc)) = k1;
#pragma unroll
    for (int j = 0; j < 8; j++) {
      *(bf16_t*)(Vt + swzel128(vdg * 16 + j, vk)) = v0[j];
      *(bf16_t*)(Vt + swzel128(vdg * 16 + 8 + j, vk)) = v1[j];
    }
  }
  __syncthreads();

  // -------- pass 2: K/V double-buffered; 1 barrier/iter --------
  for (int kt = 0; kt < 16; kt++) {
    const int cur = (kt & 1) * 8192;
    const int nxt = ((kt + 1) & 1) * 8192;
    bf16x8 kr0, kr1, vr0, vr1;
    if (kt < 15) {               // early-issue next K,V loads (hide under compute)
      const bf16_t* kp = Kg + (long)((kt + 1) * 64 + sr) * 2304 + sc * 8;
      kr0 = *(const bf16x8*)(kp);
      kr1 = *(const bf16x8*)(kp + 32);
      const bf16_t* vp = Vg + (long)((kt + 1) * 64 + vk) * 2304 + vdg * 16;
      vr0 = *(const bf16x8*)(vp);
      vr1 = *(const bf16x8*)(vp + 8);
    }
    f32x4 sfr[4];
    computeS(Ks + cur, sfr);
#pragma unroll
    for (int f = 0; f < 4; f++)
#pragma unroll
      for (int r = 0; r < 4; r++) {
        float p = exp2f(sfr[f][r]) * il[r];
        *(bf16_t*)(Pw + swzel128(lk * 4 + r, f * 16 + lrow)) = (bf16_t)p;
      }
    // PV (own Pw, lgkm-ordered within wave; Vt[cur] published at prior barrier)
#pragma unroll
    for (int kk = 0; kk < 2; kk++) {
      bf16x8 pf = *(const bf16x8*)(Pw + swz128(lrow, kk * 4 + lk));
#pragma unroll
      for (int f = 0; f < 4; f++) {
        bf16x8 vf = *(const bf16x8*)(Vt + cur + swz128(f * 16 + lrow, kk * 4 + lk));
        of[f] = mfma16(pf, vf, of[f]);
      }
    }
    // DENSE NT attn stores from own Pw
    float* ab = attn_base + kt * 64;
    {
      const int rsub = lane >> 4;
      const int c8 = lane & 15;
      const char* psrc = Pw + (c8 & 1) * 8;
#pragma unroll
      for (int i = 0; i < 4; i++) {
        int rl = i * 4 + rsub;
        bf16x4 pv = *(const bf16x4*)(psrc + swz128(rl, c8 >> 1));
        f32x4 v = {(float)pv[0], (float)pv[1], (float)pv[2], (float)pv[3]};
        __builtin_nontemporal_store(
            v, (f32x4*)(ab + ((long)(wave * 16 + rl) << 10) + c8 * 4));
      }
    }
    if (kt < 15) {               // stage next tiles into OTHER buffers
      *(bf16x8*)(Ks + nxt + swz128(sr, sc)) = kr0;
      *(bf16x8*)(Ks + nxt + swz128(sr, 4 + sc)) = kr1;
#pragma unroll
      for (int j = 0; j < 8; j++) {
        *(bf16_t*)(Vt + nxt + swzel128(vdg * 16 + j, vk)) = vr0[j];
        *(bf16_t*)(Vt + nxt + swzel128(vdg * 16 + 8 + j, vk)) = vr1[j];
      }
    }
    __syncthreads();             // publish nxt; free cur
  }

  // epilogue: out_heads [B,N,C] bf16
#pragma unroll
  for (int f = 0; f < 4; f++)
#pragma unroll
    for (int r = 0; r < 4; r++) {
      int nrow = qt * 64 + wave * 16 + lk * 4 + r;
      int d = f * 16 + lrow;
      out_heads[((long)b * 1024 + nrow) * 768 + h * 64 + d] = (bf16_t)of[f][r];
    }
}

// ---------------- launcher ----------------
extern "C" void kernel_launch(void* const* d_in, const int* in_sizes, int n_in,
                              void* d_out, int out_size, void* d_ws, size_t ws_size,
                              hipStream_t stream) {
  (void)in_sizes; (void)n_in; (void)out_size; (void)ws_size;
  const float* x       = (const float*)d_in[0];
  const float* qkv_w   = (const float*)d_in[1];
  const float* qkv_b   = (const float*)d_in[2];
  const float* q_gamma = (const float*)d_in[3];
  const float* q_beta  = (const float*)d_in[4];
  const float* k_gamma = (const float*)d_in[5];
  const float* k_beta  = (const float*)d_in[6];
  const float* proj_w  = (const float*)d_in[7];
  const float* proj_b  = (const float*)d_in[8];
  float* out = (float*)d_out;

  char* ws = (char*)d_ws;
  bf16_t* x_bf      = (bf16_t*)(ws);               // 12,582,912 B
  bf16_t* wqkv      = (bf16_t*)(ws + 12582912L);   //  3,538,944 B
  bf16_t* wproj     = (bf16_t*)(ws + 16121856L);   //  1,179,648 B
  bf16_t* qkv       = (bf16_t*)(ws + 17301504L);   // 37,748,736 B
  bf16_t* out_heads = (bf16_t*)(ws + 55050240L);   // 12,582,912 B

  cast_all<<<4224, 256, 0, stream>>>(x, x_bf, qkv_w, wqkv, proj_w, wproj);
  gemm_qkv_ln<<<dim3(18, 64), 256, 0, stream>>>(x_bf, wqkv, qkv_b,
                                                q_gamma, q_beta, k_gamma, k_beta,
                                                qkv, 8192, 2304, 768);
  attn_kernel<<<1536, 256, 0, stream>>>(qkv, out + 6291456L, out_heads);
  gemm_bt<<<dim3(6, 64), 256, 0, stream>>>(out_heads, wproj, proj_b, out, 8192, 768, 768);
}

// Round 19
// 182.423 us; speedup vs baseline: 1.1174x; 1.0762x over previous
//
#include <hip/hip_runtime.h>
#include <hip/hip_bf16.h>
#include <stdint.h>

typedef __bf16 bf16_t;
typedef __bf16 bf16x8 __attribute__((ext_vector_type(8)));
typedef __bf16 bf16x4 __attribute__((ext_vector_type(4)));
typedef float f32x4 __attribute__((ext_vector_type(4)));

#define DEV static __device__ __forceinline__

DEV f32x4 mfma16(bf16x8 a, bf16x8 b, f32x4 c) {
  return __builtin_amdgcn_mfma_f32_16x16x32_bf16(a, b, c, 0, 0, 0);
}

// async global->LDS, 16B per lane. dst wave-uniform; HW adds lane*16.
DEV void gll16(const void* g, void* l) {
  __builtin_amdgcn_global_load_lds(
      (const __attribute__((address_space(1))) uint32_t*)g,
      (__attribute__((address_space(3))) uint32_t*)l, 16, 0, 0);
}

// swizzles for 128B-row LDS tiles (XOR 16B-block idx with row low bits)
DEV int swz128(int row, int c16) {
  return (row << 7) + (((c16 ^ row) & 7) << 4);
}
DEV int swzel128(int row, int col) {
  return (row << 7) + ((((col >> 3) ^ row) & 7) << 4) + ((col & 7) << 1);
}

// stage a 64x64-bf16 tile (global row stride = rstride elems) into LDS,
// linear dest via global_load_lds + inverse-swizzled per-lane SOURCE (rule 21).
// LDS content at (row, b) = global(row, c16 = b ^ (row&7)); read with swz128.
DEV void stage_tile_gll(const bf16_t* g, long rstride, char* lds, int wave, int lane) {
  int r0 = wave * 8 + (lane >> 3);
  int b = lane & 7;
#pragma unroll
  for (int q = 0; q < 2; q++) {
    int row = q * 32 + r0;
    gll16(g + (long)row * rstride + (((b ^ row) & 7) << 3),
          lds + q * 4096 + wave * 1024);
  }
}

// ---------------- fused cast fp32 -> bf16 (x, qkv_w, proj_w) ----------------
__global__ void __launch_bounds__(256)
cast_all(const float* __restrict__ x, bf16_t* __restrict__ ox,
         const float* __restrict__ w1, bf16_t* __restrict__ ow1,
         const float* __restrict__ w2, bf16_t* __restrict__ ow2) {
  long i = (long)(blockIdx.x * 256 + threadIdx.x) * 8;
  const float* s; bf16_t* d; long off;
  if (i < 6291456L)      { s = x;  d = ox;  off = i; }
  else if (i < 8060928L) { s = w1; d = ow1; off = i - 6291456L; }
  else if (i < 8650752L) { s = w2; d = ow2; off = i - 8060928L; }
  else return;
  float4 a = *(const float4*)(s + off);
  float4 b = *(const float4*)(s + off + 4);
  bf16x8 v;
  v[0] = (bf16_t)a.x; v[1] = (bf16_t)a.y; v[2] = (bf16_t)a.z; v[3] = (bf16_t)a.w;
  v[4] = (bf16_t)b.x; v[5] = (bf16_t)b.y; v[6] = (bf16_t)b.z; v[7] = (bf16_t)b.w;
  *(bf16x8*)(d + off) = v;
}

// SCALE * log2(e): q pre-scaled so attn uses exp2 directly
#define C1Q 0.1803368801111244f

// ---------------- qkv GEMM, BK=64 (swizzled gll staging), fused per-head LN ----------------
// BK 32->64: halves barrier count (48->24), doubles MFMA per barrier. LDS 32KB
// per block keeps 2 blocks/CU (m132's BK=128 failure was the 64KB/block cliff).
// Staging reuses the verified stage_tile_gll + swz128 pair (rule 21).
__global__ void __launch_bounds__(256, 2)
gemm_qkv_ln(const bf16_t* __restrict__ A, const bf16_t* __restrict__ Bw,
            const float* __restrict__ bias,
            const float* __restrict__ qg, const float* __restrict__ qb,
            const float* __restrict__ kg, const float* __restrict__ kb,
            bf16_t* __restrict__ qkv, int M, int N, int K) {
  __shared__ __align__(16) char As[16384];   // two 64x64 tiles (M 0-63, 64-127)
  __shared__ __align__(16) char Bs[16384];
  const int tid = threadIdx.x;
  const int lane = tid & 63;
  const int wave = tid >> 6;
  const int wr = wave >> 1, wc = wave & 1;
  const int tileM = blockIdx.y << 7;
  const int tileN = blockIdx.x << 7;
  const int lrow = lane & 15, lk = lane >> 4;

  f32x4 acc[4][4];
  f32x4 z = {0.f, 0.f, 0.f, 0.f};
#pragma unroll
  for (int m = 0; m < 4; m++)
#pragma unroll
    for (int n = 0; n < 4; n++) acc[m][n] = z;

  for (int k0 = 0; k0 < K; k0 += 64) {
    __syncthreads();                 // prior-tile LDS reads complete
    stage_tile_gll(A + (long)tileM * K + k0, K, As, wave, lane);
    stage_tile_gll(A + (long)(tileM + 64) * K + k0, K, As + 8192, wave, lane);
    stage_tile_gll(Bw + (long)tileN * K + k0, K, Bs, wave, lane);
    stage_tile_gll(Bw + (long)(tileN + 64) * K + k0, K, Bs + 8192, wave, lane);
    __syncthreads();                 // vmcnt(0) drain -> tiles ready
#pragma unroll
    for (int ks = 0; ks < 2; ks++) {
      bf16x8 af[4], bfr[4];
#pragma unroll
      for (int m = 0; m < 4; m++)
        af[m] = *(const bf16x8*)(As + wr * 8192 + swz128(m * 16 + lrow, ks * 4 + lk));
#pragma unroll
      for (int n = 0; n < 4; n++)
        bfr[n] = *(const bf16x8*)(Bs + wc * 8192 + swz128(n * 16 + lrow, ks * 4 + lk));
#pragma unroll
      for (int m = 0; m < 4; m++)
#pragma unroll
        for (int n = 0; n < 4; n++)
          acc[m][n] = mfma16(af[m], bfr[n], acc[m][n]);
    }
  }

  const int t = tileN / 768;
  const int cbase = tileN + wc * 64;
  float g[4], be[4], bv[4];
#pragma unroll
  for (int n = 0; n < 4; n++) bv[n] = bias[cbase + n * 16 + lrow];
  if (t == 0) {
#pragma unroll
    for (int n = 0; n < 4; n++) {
      int d = n * 16 + lrow;
      g[n] = qg[d] * C1Q; be[n] = qb[d] * C1Q;
    }
  } else if (t == 1) {
#pragma unroll
    for (int n = 0; n < 4; n++) {
      int d = n * 16 + lrow;
      g[n] = kg[d]; be[n] = kb[d];
    }
  }

#pragma unroll
  for (int m = 0; m < 4; m++) {
#pragma unroll
    for (int r = 0; r < 4; r++) {
      float v[4];
#pragma unroll
      for (int n = 0; n < 4; n++) v[n] = acc[m][n][r] + bv[n];
      long row = tileM + wr * 64 + m * 16 + lk * 4 + r;
      bf16_t* dst = qkv + row * 2304 + cbase;
      if (t < 2) {
        float s = v[0] + v[1] + v[2] + v[3];
        float s2 = v[0]*v[0] + v[1]*v[1] + v[2]*v[2] + v[3]*v[3];
#pragma unroll
        for (int ofs = 1; ofs <= 8; ofs <<= 1) {
          s  += __shfl_xor(s, ofs);
          s2 += __shfl_xor(s2, ofs);
        }
        float mu = s * (1.f / 64.f);
        float rstd = rsqrtf(s2 * (1.f / 64.f) - mu * mu + 1e-5f);
#pragma unroll
        for (int n = 0; n < 4; n++)
          dst[n * 16 + lrow] = (bf16_t)((v[n] - mu) * rstd * g[n] + be[n]);
      } else {
#pragma unroll
        for (int n = 0; n < 4; n++)
          dst[n * 16 + lrow] = (bf16_t)v[n];
      }
    }
  }
}

// ---------------- proj GEMM, BK=64: C = A * Bw^T + bias, fp32 out ----------------
__global__ void __launch_bounds__(256, 2)
gemm_bt(const bf16_t* __restrict__ A, const bf16_t* __restrict__ Bw,
        const float* __restrict__ bias, float* __restrict__ Cout,
        int M, int N, int K) {
  __shared__ __align__(16) char As[16384];
  __shared__ __align__(16) char Bs[16384];
  const int tid = threadIdx.x;
  const int lane = tid & 63;
  const int wave = tid >> 6;
  const int wr = wave >> 1, wc = wave & 1;
  const int tileM = blockIdx.y << 7;
  const int tileN = blockIdx.x << 7;
  const int lrow = lane & 15, lk = lane >> 4;

  f32x4 acc[4][4];
  f32x4 z = {0.f, 0.f, 0.f, 0.f};
#pragma unroll
  for (int m = 0; m < 4; m++)
#pragma unroll
    for (int n = 0; n < 4; n++) acc[m][n] = z;

  for (int k0 = 0; k0 < K; k0 += 64) {
    __syncthreads();
    stage_tile_gll(A + (long)tileM * K + k0, K, As, wave, lane);
    stage_tile_gll(A + (long)(tileM + 64) * K + k0, K, As + 8192, wave, lane);
    stage_tile_gll(Bw + (long)tileN * K + k0, K, Bs, wave, lane);
    stage_tile_gll(Bw + (long)(tileN + 64) * K + k0, K, Bs + 8192, wave, lane);
    __syncthreads();
#pragma unroll
    for (int ks = 0; ks < 2; ks++) {
      bf16x8 af[4], bfr[4];
#pragma unroll
      for (int m = 0; m < 4; m++)
        af[m] = *(const bf16x8*)(As + wr * 8192 + swz128(m * 16 + lrow, ks * 4 + lk));
#pragma unroll
      for (int n = 0; n < 4; n++)
        bfr[n] = *(const bf16x8*)(Bs + wc * 8192 + swz128(n * 16 + lrow, ks * 4 + lk));
#pragma unroll
      for (int m = 0; m < 4; m++)
#pragma unroll
        for (int n = 0; n < 4; n++)
          acc[m][n] = mfma16(af[m], bfr[n], acc[m][n]);
    }
  }

  const int rg = lk;
#pragma unroll
  for (int n = 0; n < 4; n++) {
    int col = tileN + wc * 64 + n * 16 + lrow;
    float bv = bias[col];
#pragma unroll
    for (int m = 0; m < 4; m++) {
      long row0 = tileM + wr * 64 + m * 16 + rg * 4;
#pragma unroll
      for (int r = 0; r < 4; r++)
        Cout[(row0 + r) * N + col] = acc[m][n][r] + bv;
    }
  }
}

// ---------------- attention: R16 verbatim (best proven: 189.0us config) ----------------
// QBLK=64, no-max softmax, dense NT stores, XCD swizzle, reg-staged K/V, 24KB LDS.
__global__ void __launch_bounds__(256, 2)
attn_kernel(const bf16_t* __restrict__ qkv, float* __restrict__ attn_out,
            bf16_t* __restrict__ out_heads) {
  const int tid = threadIdx.x;
  const int lane = tid & 63;
  const int wave = tid >> 6;
  const int lb = blockIdx.x;            // 0..1535
  const int sid = (lb & 7) * 192 + (lb >> 3);   // bijective XCD-chunk swizzle
  const int qt = sid & 15;
  const int bh = sid >> 4;
  const int b = bh / 12, h = bh - b * 12;

  const bf16_t* base = qkv + (long)b * 2359296L + h * 64;
  const bf16_t* Qg = base;
  const bf16_t* Kg = base + 768;
  const bf16_t* Vg = base + 1536;

  __shared__ __align__(16) char Ks[8192];   // K buffer A (pass2: the K buffer)
  __shared__ __align__(16) char Vt[8192];   // pass1: K buffer B; pass2: V^T tile
  __shared__ __align__(16) char QP[8192];   // prologue: Q; then per-wave P

  const int lrow = lane & 15;
  const int lk = lane >> 4;
  const int sr = tid >> 2;      // staging row 0..63
  const int sc = tid & 3;       // staging 16B chunk (and sc+4)

  // prologue: reg-stage Q and K0 (coalesced 64B/row segments)
  {
    const bf16_t* qp = Qg + (long)(qt * 64 + sr) * 2304 + sc * 8;
    const bf16_t* kp = Kg + (long)sr * 2304 + sc * 8;
    bf16x8 q0 = *(const bf16x8*)(qp);
    bf16x8 q1 = *(const bf16x8*)(qp + 32);
    bf16x8 k0 = *(const bf16x8*)(kp);
    bf16x8 k1 = *(const bf16x8*)(kp + 32);
    *(bf16x8*)(QP + swz128(sr, sc)) = q0;
    *(bf16x8*)(QP + swz128(sr, 4 + sc)) = q1;
    *(bf16x8*)(Ks + swz128(sr, sc)) = k0;
    *(bf16x8*)(Ks + swz128(sr, 4 + sc)) = k1;
  }
  __syncthreads();

  bf16x8 qf[2];
  qf[0] = *(const bf16x8*)(QP + swz128(wave * 16 + lrow, lk));
  qf[1] = *(const bf16x8*)(QP + swz128(wave * 16 + lrow, 4 + lk));

  auto computeS = [&](const char* Kb, f32x4 sfr[4]) {
    f32x4 z = {0.f, 0.f, 0.f, 0.f};
    sfr[0] = z; sfr[1] = z; sfr[2] = z; sfr[3] = z;
#pragma unroll
    for (int kk = 0; kk < 2; kk++)
#pragma unroll
      for (int f = 0; f < 4; f++) {
        bf16x8 kf = *(const bf16x8*)(Kb + swz128(f * 16 + lrow, kk * 4 + lk));
        sfr[f] = mfma16(qf[kk], kf, sfr[f]);
      }
  };

  float l_r[4] = {0.f, 0.f, 0.f, 0.f};

  // -------- pass 1: K double-buffered across Ks<->Vt; 1 barrier/iter --------
  for (int kt = 0; kt < 16; kt++) {
    const char* cur = (kt & 1) ? Vt : Ks;
    bf16x8 kr0, kr1;
    if (kt < 15) {
      const bf16_t* kp = Kg + (long)((kt + 1) * 64 + sr) * 2304 + sc * 8;
      kr0 = *(const bf16x8*)(kp);
      kr1 = *(const bf16x8*)(kp + 32);
    }
    f32x4 sfr[4];
    computeS(cur, sfr);
#pragma unroll
    for (int r = 0; r < 4; r++)
      l_r[r] += exp2f(sfr[0][r]) + exp2f(sfr[1][r]) +
                exp2f(sfr[2][r]) + exp2f(sfr[3][r]);
    if (kt < 15) {
      char* nxt = (kt & 1) ? Ks : Vt;
      *(bf16x8*)(nxt + swz128(sr, sc)) = kr0;
      *(bf16x8*)(nxt + swz128(sr, 4 + sc)) = kr1;
    }
    __syncthreads();
  }

  float il[4];
#pragma unroll
  for (int r = 0; r < 4; r++) {
#pragma unroll
    for (int ofs = 1; ofs <= 8; ofs <<= 1)
      l_r[r] += __shfl_xor(l_r[r], ofs);
    il[r] = 1.0f / l_r[r];
  }

  f32x4 of[4];
  {
    f32x4 z = {0.f, 0.f, 0.f, 0.f};
    of[0] = z; of[1] = z; of[2] = z; of[3] = z;
  }
  char* Pw = QP + wave * 2048;
  float* attn_base = attn_out + (long)bh * 1048576 + ((long)(qt * 64) << 10);

  // pass-2 prologue: stage K0 -> Ks (packed) and V0^T -> Vt (scatter)
  const int vk = lane, vdg = wave;
  {
    const bf16_t* kp = Kg + (long)sr * 2304 + sc * 8;
    bf16x8 k0 = *(const bf16x8*)(kp);
    bf16x8 k1 = *(const bf16x8*)(kp + 32);
    const bf16_t* vp = Vg + (long)vk * 2304 + vdg * 16;
    bf16x8 v0 = *(const bf16x8*)(vp);
    bf16x8 v1 = *(const bf16x8*)(vp + 8);
    *(bf16x8*)(Ks + swz128(sr, sc)) = k0;
    *(bf16x8*)(Ks + swz128(sr, 4 + sc)) = k1;
#pragma unroll
    for (int j = 0; j < 8; j++) {
      *(bf16_t*)(Vt + swzel128(vdg * 16 + j, vk)) = v0[j];
      *(bf16_t*)(Vt + swzel128(vdg * 16 + 8 + j, vk)) = v1[j];
    }
  }
  __syncthreads();

  // -------- pass 2: compute from Ks/Vt; re-stage after barrier; 2 barriers/iter ----
  for (int kt = 0; kt < 16; kt++) {
    bf16x8 kr0, kr1, vr0, vr1;
    if (kt < 15) {               // early-issue next K,V loads (hide under compute)
      const bf16_t* kp = Kg + (long)((kt + 1) * 64 + sr) * 2304 + sc * 8;
      kr0 = *(const bf16x8*)(kp);
      kr1 = *(const bf16x8*)(kp + 32);
      const bf16_t* vp = Vg + (long)((kt + 1) * 64 + vk) * 2304 + vdg * 16;
      vr0 = *(const bf16x8*)(vp);
      vr1 = *(const bf16x8*)(vp + 8);
    }
    f32x4 sfr[4];
    computeS(Ks, sfr);
#pragma unroll
    for (int f = 0; f < 4; f++)
#pragma unroll
      for (int r = 0; r < 4; r++) {
        float p = exp2f(sfr[f][r]) * il[r];
        *(bf16_t*)(Pw + swzel128(lk * 4 + r, f * 16 + lrow)) = (bf16_t)p;
      }
    // PV (own Pw ordered by lgkmcnt; Vt published at prior barrier)
#pragma unroll
    for (int kk = 0; kk < 2; kk++) {
      bf16x8 pf = *(const bf16x8*)(Pw + swz128(lrow, kk * 4 + lk));
#pragma unroll
      for (int f = 0; f < 4; f++) {
        bf16x8 vf = *(const bf16x8*)(Vt + swz128(f * 16 + lrow, kk * 4 + lk));
        of[f] = mfma16(pf, vf, of[f]);
      }
    }
    // DENSE NT attn stores from own Pw
    float* ab = attn_base + kt * 64;
    {
      const int rsub = lane >> 4;
      const int c8 = lane & 15;
      const char* psrc = Pw + (c8 & 1) * 8;
#pragma unroll
      for (int i = 0; i < 4; i++) {
        int rl = i * 4 + rsub;
        bf16x4 pv = *(const bf16x4*)(psrc + swz128(rl, c8 >> 1));
        f32x4 v = {(float)pv[0], (float)pv[1], (float)pv[2], (float)pv[3]};
        __builtin_nontemporal_store(
            v, (f32x4*)(ab + ((long)(wave * 16 + rl) << 10) + c8 * 4));
      }
    }
    __syncthreads();             // all waves done reading Ks, Vt
    if (kt < 15) {               // re-stage next tiles
      *(bf16x8*)(Ks + swz128(sr, sc)) = kr0;
      *(bf16x8*)(Ks + swz128(sr, 4 + sc)) = kr1;
#pragma unroll
      for (int j = 0; j < 8; j++) {
        *(bf16_t*)(Vt + swzel128(vdg * 16 + j, vk)) = vr0[j];
        *(bf16_t*)(Vt + swzel128(vdg * 16 + 8 + j, vk)) = vr1[j];
      }
    }
    __syncthreads();             // publish
  }

  // epilogue: out_heads [B,N,C] bf16
#pragma unroll
  for (int f = 0; f < 4; f++)
#pragma unroll
    for (int r = 0; r < 4; r++) {
      int nrow = qt * 64 + wave * 16 + lk * 4 + r;
      int d = f * 16 + lrow;
      out_heads[((long)b * 1024 + nrow) * 768 + h * 64 + d] = (bf16_t)of[f][r];
    }
}

// ---------------- launcher ----------------
extern "C" void kernel_launch(void* const* d_in, const int* in_sizes, int n_in,
                              void* d_out, int out_size, void* d_ws, size_t ws_size,
                              hipStream_t stream) {
  (void)in_sizes; (void)n_in; (void)out_size; (void)ws_size;
  const float* x       = (const float*)d_in[0];
  const float* qkv_w   = (const float*)d_in[1];
  const float* qkv_b   = (const float*)d_in[2];
  const float* q_gamma = (const float*)d_in[3];
  const float* q_beta  = (const float*)d_in[4];
  const float* k_gamma = (const float*)d_in[5];
  const float* k_beta  = (const float*)d_in[6];
  const float* proj_w  = (const float*)d_in[7];
  const float* proj_b  = (const float*)d_in[8];
  float* out = (float*)d_out;

  char* ws = (char*)d_ws;
  bf16_t* x_bf      = (bf16_t*)(ws);               // 12,582,912 B
  bf16_t* wqkv      = (bf16_t*)(ws + 12582912L);   //  3,538,944 B
  bf16_t* wproj     = (bf16_t*)(ws + 16121856L);   //  1,179,648 B
  bf16_t* qkv       = (bf16_t*)(ws + 17301504L);   // 37,748,736 B
  bf16_t* out_heads = (bf16_t*)(ws + 55050240L);   // 12,582,912 B

  cast_all<<<4224, 256, 0, stream>>>(x, x_bf, qkv_w, wqkv, proj_w, wproj);
  gemm_qkv_ln<<<dim3(18, 64), 256, 0, stream>>>(x_bf, wqkv, qkv_b,
                                                q_gamma, q_beta, k_gamma, k_beta,
                                                qkv, 8192, 2304, 768);
  attn_kernel<<<1536, 256, 0, stream>>>(qkv, out + 6291456L, out_heads);
  gemm_bt<<<dim3(6, 64), 256, 0, stream>>>(out_heads, wproj, proj_b, out, 8192, 768, 768);
}

// Round 20
// 177.297 us; speedup vs baseline: 1.1497x; 1.0289x over previous
//
#include <hip/hip_runtime.h>
#include <hip/hip_bf16.h>
#include <stdint.h>

typedef __bf16 bf16_t;
typedef __bf16 bf16x8 __attribute__((ext_vector_type(8)));
typedef __bf16 bf16x4 __attribute__((ext_vector_type(4)));
typedef float f32x4 __attribute__((ext_vector_type(4)));

#define DEV static __device__ __forceinline__

DEV f32x4 mfma16(bf16x8 a, bf16x8 b, f32x4 c) {
  return __builtin_amdgcn_mfma_f32_16x16x32_bf16(a, b, c, 0, 0, 0);
}

// async global->LDS, 16B per lane. dst wave-uniform; HW adds lane*16.
DEV void gll16(const void* g, void* l) {
  __builtin_amdgcn_global_load_lds(
      (const __attribute__((address_space(1))) uint32_t*)g,
      (__attribute__((address_space(3))) uint32_t*)l, 16, 0, 0);
}

// swizzles for 128B-row LDS tiles (XOR 16B-block idx with row low bits)
DEV int swz128(int row, int c16) {
  return (row << 7) + (((c16 ^ row) & 7) << 4);
}
DEV int swzel128(int row, int col) {
  return (row << 7) + ((((col >> 3) ^ row) & 7) << 4) + ((col & 7) << 1);
}

// stage a 64x64-bf16 tile (global row stride = rstride elems) into LDS,
// linear dest via global_load_lds + inverse-swizzled per-lane SOURCE (rule 21).
DEV void stage_tile_gll(const bf16_t* g, long rstride, char* lds, int wave, int lane) {
  int r0 = wave * 8 + (lane >> 3);
  int b = lane & 7;
#pragma unroll
  for (int q = 0; q < 2; q++) {
    int row = q * 32 + r0;
    gll16(g + (long)row * rstride + (((b ^ row) & 7) << 3),
          lds + q * 4096 + wave * 1024);
  }
}

// ---------------- fused cast fp32 -> bf16 (x, qkv_w, proj_w) ----------------
__global__ void __launch_bounds__(256)
cast_all(const float* __restrict__ x, bf16_t* __restrict__ ox,
         const float* __restrict__ w1, bf16_t* __restrict__ ow1,
         const float* __restrict__ w2, bf16_t* __restrict__ ow2) {
  long i = (long)(blockIdx.x * 256 + threadIdx.x) * 8;
  const float* s; bf16_t* d; long off;
  if (i < 6291456L)      { s = x;  d = ox;  off = i; }
  else if (i < 8060928L) { s = w1; d = ow1; off = i - 6291456L; }
  else if (i < 8650752L) { s = w2; d = ow2; off = i - 8060928L; }
  else return;
  float4 a = *(const float4*)(s + off);
  float4 b = *(const float4*)(s + off + 4);
  bf16x8 v;
  v[0] = (bf16_t)a.x; v[1] = (bf16_t)a.y; v[2] = (bf16_t)a.z; v[3] = (bf16_t)a.w;
  v[4] = (bf16_t)b.x; v[5] = (bf16_t)b.y; v[6] = (bf16_t)b.z; v[7] = (bf16_t)b.w;
  *(bf16x8*)(d + off) = v;
}

// SCALE * log2(e): q pre-scaled so attn uses exp2 directly
#define C1Q 0.1803368801111244f

// ---------------- qkv GEMM, BK=64 (swizzled gll staging), fused per-head LN ----------------
__global__ void __launch_bounds__(256, 2)
gemm_qkv_ln(const bf16_t* __restrict__ A, const bf16_t* __restrict__ Bw,
            const float* __restrict__ bias,
            const float* __restrict__ qg, const float* __restrict__ qb,
            const float* __restrict__ kg, const float* __restrict__ kb,
            bf16_t* __restrict__ qkv, int M, int N, int K) {
  __shared__ __align__(16) char As[16384];
  __shared__ __align__(16) char Bs[16384];
  const int tid = threadIdx.x;
  const int lane = tid & 63;
  const int wave = tid >> 6;
  const int wr = wave >> 1, wc = wave & 1;
  const int tileM = blockIdx.y << 7;
  const int tileN = blockIdx.x << 7;
  const int lrow = lane & 15, lk = lane >> 4;

  f32x4 acc[4][4];
  f32x4 z = {0.f, 0.f, 0.f, 0.f};
#pragma unroll
  for (int m = 0; m < 4; m++)
#pragma unroll
    for (int n = 0; n < 4; n++) acc[m][n] = z;

  for (int k0 = 0; k0 < K; k0 += 64) {
    __syncthreads();
    stage_tile_gll(A + (long)tileM * K + k0, K, As, wave, lane);
    stage_tile_gll(A + (long)(tileM + 64) * K + k0, K, As + 8192, wave, lane);
    stage_tile_gll(Bw + (long)tileN * K + k0, K, Bs, wave, lane);
    stage_tile_gll(Bw + (long)(tileN + 64) * K + k0, K, Bs + 8192, wave, lane);
    __syncthreads();
#pragma unroll
    for (int ks = 0; ks < 2; ks++) {
      bf16x8 af[4], bfr[4];
#pragma unroll
      for (int m = 0; m < 4; m++)
        af[m] = *(const bf16x8*)(As + wr * 8192 + swz128(m * 16 + lrow, ks * 4 + lk));
#pragma unroll
      for (int n = 0; n < 4; n++)
        bfr[n] = *(const bf16x8*)(Bs + wc * 8192 + swz128(n * 16 + lrow, ks * 4 + lk));
#pragma unroll
      for (int m = 0; m < 4; m++)
#pragma unroll
        for (int n = 0; n < 4; n++)
          acc[m][n] = mfma16(af[m], bfr[n], acc[m][n]);
    }
  }

  const int t = tileN / 768;
  const int cbase = tileN + wc * 64;
  float g[4], be[4], bv[4];
#pragma unroll
  for (int n = 0; n < 4; n++) bv[n] = bias[cbase + n * 16 + lrow];
  if (t == 0) {
#pragma unroll
    for (int n = 0; n < 4; n++) {
      int d = n * 16 + lrow;
      g[n] = qg[d] * C1Q; be[n] = qb[d] * C1Q;
    }
  } else if (t == 1) {
#pragma unroll
    for (int n = 0; n < 4; n++) {
      int d = n * 16 + lrow;
      g[n] = kg[d]; be[n] = kb[d];
    }
  }

#pragma unroll
  for (int m = 0; m < 4; m++) {
#pragma unroll
    for (int r = 0; r < 4; r++) {
      float v[4];
#pragma unroll
      for (int n = 0; n < 4; n++) v[n] = acc[m][n][r] + bv[n];
      long row = tileM + wr * 64 + m * 16 + lk * 4 + r;
      bf16_t* dst = qkv + row * 2304 + cbase;
      if (t < 2) {
        float s = v[0] + v[1] + v[2] + v[3];
        float s2 = v[0]*v[0] + v[1]*v[1] + v[2]*v[2] + v[3]*v[3];
#pragma unroll
        for (int ofs = 1; ofs <= 8; ofs <<= 1) {
          s  += __shfl_xor(s, ofs);
          s2 += __shfl_xor(s2, ofs);
        }
        float mu = s * (1.f / 64.f);
        float rstd = rsqrtf(s2 * (1.f / 64.f) - mu * mu + 1e-5f);
#pragma unroll
        for (int n = 0; n < 4; n++)
          dst[n * 16 + lrow] = (bf16_t)((v[n] - mu) * rstd * g[n] + be[n]);
      } else {
#pragma unroll
        for (int n = 0; n < 4; n++)
          dst[n * 16 + lrow] = (bf16_t)v[n];
      }
    }
  }
}

// ---------------- proj GEMM, BK=64: C = A * Bw^T + bias, fp32 out ----------------
__global__ void __launch_bounds__(256, 2)
gemm_bt(const bf16_t* __restrict__ A, const bf16_t* __restrict__ Bw,
        const float* __restrict__ bias, float* __restrict__ Cout,
        int M, int N, int K) {
  __shared__ __align__(16) char As[16384];
  __shared__ __align__(16) char Bs[16384];
  const int tid = threadIdx.x;
  const int lane = tid & 63;
  const int wave = tid >> 6;
  const int wr = wave >> 1, wc = wave & 1;
  const int tileM = blockIdx.y << 7;
  const int tileN = blockIdx.x << 7;
  const int lrow = lane & 15, lk = lane >> 4;

  f32x4 acc[4][4];
  f32x4 z = {0.f, 0.f, 0.f, 0.f};
#pragma unroll
  for (int m = 0; m < 4; m++)
#pragma unroll
    for (int n = 0; n < 4; n++) acc[m][n] = z;

  for (int k0 = 0; k0 < K; k0 += 64) {
    __syncthreads();
    stage_tile_gll(A + (long)tileM * K + k0, K, As, wave, lane);
    stage_tile_gll(A + (long)(tileM + 64) * K + k0, K, As + 8192, wave, lane);
    stage_tile_gll(Bw + (long)tileN * K + k0, K, Bs, wave, lane);
    stage_tile_gll(Bw + (long)(tileN + 64) * K + k0, K, Bs + 8192, wave, lane);
    __syncthreads();
#pragma unroll
    for (int ks = 0; ks < 2; ks++) {
      bf16x8 af[4], bfr[4];
#pragma unroll
      for (int m = 0; m < 4; m++)
        af[m] = *(const bf16x8*)(As + wr * 8192 + swz128(m * 16 + lrow, ks * 4 + lk));
#pragma unroll
      for (int n = 0; n < 4; n++)
        bfr[n] = *(const bf16x8*)(Bs + wc * 8192 + swz128(n * 16 + lrow, ks * 4 + lk));
#pragma unroll
      for (int m = 0; m < 4; m++)
#pragma unroll
        for (int n = 0; n < 4; n++)
          acc[m][n] = mfma16(af[m], bfr[n], acc[m][n]);
    }
  }

  const int rg = lk;
#pragma unroll
  for (int n = 0; n < 4; n++) {
    int col = tileN + wc * 64 + n * 16 + lrow;
    float bv = bias[col];
#pragma unroll
    for (int m = 0; m < 4; m++) {
      long row0 = tileM + wr * 64 + m * 16 + rg * 4;
#pragma unroll
      for (int r = 0; r < 4; r++)
        Cout[(row0 + r) * N + col] = acc[m][n][r] + bv;
    }
  }
}

// ---------------- attention: QBLK=128 @ 512 threads (8 waves x 16 rows) ----------------
// R6/R17's QBLK=128 failures halved TOTAL waves (768 x 4). This keeps 6144 waves
// (768 x 8) -- per-wave work identical to R16; K/V staged once per 128 q-rows
// (halved staging instructions + L2 traffic); waves/CU rises (~24 vs ~11).
// Same two-pass / barrier discipline, dense NT stores, no-max softmax, XCD swizzle.
__global__ void __launch_bounds__(512)
attn_kernel(const bf16_t* __restrict__ qkv, float* __restrict__ attn_out,
            bf16_t* __restrict__ out_heads) {
  const int tid = threadIdx.x;
  const int lane = tid & 63;
  const int wave = tid >> 6;            // 0..7
  const int lb = blockIdx.x;            // 0..767
  const int sid = (lb & 7) * 96 + (lb >> 3);    // bijective XCD-chunk swizzle
  const int qt = sid & 7;               // 8 q-tiles of 128 rows
  const int bh = sid >> 3;              // 96 heads
  const int b = bh / 12, h = bh - b * 12;

  const bf16_t* base = qkv + (long)b * 2359296L + h * 64;
  const bf16_t* Qg = base;
  const bf16_t* Kg = base + 768;
  const bf16_t* Vg = base + 1536;

  __shared__ __align__(16) char QP[16384];  // Q 128x64; pass2: per-wave P (16x64 each)
  __shared__ __align__(16) char Ks[8192];   // K buffer A
  __shared__ __align__(16) char Vt[8192];   // pass1: K buffer B; pass2: V^T

  const int lrow = lane & 15;
  const int lk = lane >> 4;
  const int qsr = tid >> 2;     // Q staging row 0..127
  const int qsc = tid & 3;      // Q staging 16B chunk (and +4)
  const int ksr = tid >> 3;     // K staging row 0..63
  const int ksc = tid & 7;      // K staging 16B chunk
  const int vk = tid & 63;      // V row within tile
  const int vdg = tid >> 6;     // V 8-col d-group (0..7)

  // prologue: reg-stage Q (128x64) and K0
  {
    const bf16_t* qp = Qg + (long)(qt * 128 + qsr) * 2304 + qsc * 8;
    bf16x8 q0 = *(const bf16x8*)(qp);
    bf16x8 q1 = *(const bf16x8*)(qp + 32);
    const bf16_t* kp = Kg + (long)ksr * 2304 + ksc * 8;
    bf16x8 k0 = *(const bf16x8*)(kp);
    *(bf16x8*)(QP + swz128(qsr, qsc)) = q0;
    *(bf16x8*)(QP + swz128(qsr, 4 + qsc)) = q1;
    *(bf16x8*)(Ks + swz128(ksr, ksc)) = k0;
  }
  __syncthreads();

  bf16x8 qf[2];
  qf[0] = *(const bf16x8*)(QP + swz128(wave * 16 + lrow, lk));
  qf[1] = *(const bf16x8*)(QP + swz128(wave * 16 + lrow, 4 + lk));

  auto computeS = [&](const char* Kb, f32x4 sfr[4]) {
    f32x4 z = {0.f, 0.f, 0.f, 0.f};
    sfr[0] = z; sfr[1] = z; sfr[2] = z; sfr[3] = z;
#pragma unroll
    for (int kk = 0; kk < 2; kk++)
#pragma unroll
      for (int f = 0; f < 4; f++) {
        bf16x8 kf = *(const bf16x8*)(Kb + swz128(f * 16 + lrow, kk * 4 + lk));
        sfr[f] = mfma16(qf[kk], kf, sfr[f]);
      }
  };

  float l_r[4] = {0.f, 0.f, 0.f, 0.f};

  // -------- pass 1: K double-buffered across Ks<->Vt; 1 barrier/iter --------
  for (int kt = 0; kt < 16; kt++) {
    const char* cur = (kt & 1) ? Vt : Ks;
    bf16x8 kr0;
    if (kt < 15) {               // early-issue next K tile load (1x16B/thread)
      kr0 = *(const bf16x8*)(Kg + (long)((kt + 1) * 64 + ksr) * 2304 + ksc * 8);
    }
    f32x4 sfr[4];
    computeS(cur, sfr);
#pragma unroll
    for (int r = 0; r < 4; r++)
      l_r[r] += exp2f(sfr[0][r]) + exp2f(sfr[1][r]) +
                exp2f(sfr[2][r]) + exp2f(sfr[3][r]);
    if (kt < 15) {               // write OTHER buffer (readers done at prev barrier)
      char* nxt = (kt & 1) ? Ks : Vt;
      *(bf16x8*)(nxt + swz128(ksr, ksc)) = kr0;
    }
    __syncthreads();
  }

  float il[4];
#pragma unroll
  for (int r = 0; r < 4; r++) {
#pragma unroll
    for (int ofs = 1; ofs <= 8; ofs <<= 1)
      l_r[r] += __shfl_xor(l_r[r], ofs);
    il[r] = 1.0f / l_r[r];
  }

  f32x4 of[4];
  {
    f32x4 z = {0.f, 0.f, 0.f, 0.f};
    of[0] = z; of[1] = z; of[2] = z; of[3] = z;
  }
  char* Pw = QP + wave * 2048;   // per-wave 16x64 P (overlays Q; qf in regs)
  float* attn_base = attn_out + (long)bh * 1048576 + ((long)(qt * 128) << 10);

  // pass-2 prologue: stage K0 -> Ks and V0^T -> Vt
  {
    const bf16_t* kp = Kg + (long)ksr * 2304 + ksc * 8;
    bf16x8 k0 = *(const bf16x8*)(kp);
    const bf16_t* vp = Vg + (long)vk * 2304 + vdg * 8;
    bf16x8 v0 = *(const bf16x8*)(vp);
    *(bf16x8*)(Ks + swz128(ksr, ksc)) = k0;
#pragma unroll
    for (int j = 0; j < 8; j++)
      *(bf16_t*)(Vt + swzel128(vdg * 8 + j, vk)) = v0[j];
  }
  __syncthreads();

  // -------- pass 2: compute from Ks/Vt; re-stage after barrier; 2 barriers/iter ----
  for (int kt = 0; kt < 16; kt++) {
    bf16x8 kr0, vr0;
    if (kt < 15) {               // early-issue next K,V loads (hide under compute)
      kr0 = *(const bf16x8*)(Kg + (long)((kt + 1) * 64 + ksr) * 2304 + ksc * 8);
      vr0 = *(const bf16x8*)(Vg + (long)((kt + 1) * 64 + vk) * 2304 + vdg * 8);
    }
    f32x4 sfr[4];
    computeS(Ks, sfr);
#pragma unroll
    for (int f = 0; f < 4; f++)
#pragma unroll
      for (int r = 0; r < 4; r++) {
        float p = exp2f(sfr[f][r]) * il[r];
        *(bf16_t*)(Pw + swzel128(lk * 4 + r, f * 16 + lrow)) = (bf16_t)p;
      }
    // PV (own Pw ordered by lgkmcnt; Vt published at prior barrier)
#pragma unroll
    for (int kk = 0; kk < 2; kk++) {
      bf16x8 pf = *(const bf16x8*)(Pw + swz128(lrow, kk * 4 + lk));
#pragma unroll
      for (int f = 0; f < 4; f++) {
        bf16x8 vf = *(const bf16x8*)(Vt + swz128(f * 16 + lrow, kk * 4 + lk));
        of[f] = mfma16(pf, vf, of[f]);
      }
    }
    // DENSE NT attn stores from own wave's P (16 rows x 64 cols)
    float* ab = attn_base + kt * 64;
    {
      const int rsub = lane >> 4;
      const int c8 = lane & 15;
      const char* psrc = Pw + (c8 & 1) * 8;
#pragma unroll
      for (int i = 0; i < 4; i++) {
        int rl = i * 4 + rsub;
        bf16x4 pv = *(const bf16x4*)(psrc + swz128(rl, c8 >> 1));
        f32x4 v = {(float)pv[0], (float)pv[1], (float)pv[2], (float)pv[3]};
        __builtin_nontemporal_store(
            v, (f32x4*)(ab + ((long)(wave * 16 + rl) << 10) + c8 * 4));
      }
    }
    __syncthreads();             // all waves done reading Ks, Vt
    if (kt < 15) {               // re-stage next tiles
      *(bf16x8*)(Ks + swz128(ksr, ksc)) = kr0;
#pragma unroll
      for (int j = 0; j < 8; j++)
        *(bf16_t*)(Vt + swzel128(vdg * 8 + j, vk)) = vr0[j];
    }
    __syncthreads();             // publish
  }

  // epilogue: out_heads [B,N,C] bf16
#pragma unroll
  for (int f = 0; f < 4; f++)
#pragma unroll
    for (int r = 0; r < 4; r++) {
      int nrow = qt * 128 + wave * 16 + lk * 4 + r;
      int d = f * 16 + lrow;
      out_heads[((long)b * 1024 + nrow) * 768 + h * 64 + d] = (bf16_t)of[f][r];
    }
}

// ---------------- launcher ----------------
extern "C" void kernel_launch(void* const* d_in, const int* in_sizes, int n_in,
                              void* d_out, int out_size, void* d_ws, size_t ws_size,
                              hipStream_t stream) {
  (void)in_sizes; (void)n_in; (void)out_size; (void)ws_size;
  const float* x       = (const float*)d_in[0];
  const float* qkv_w   = (const float*)d_in[1];
  const float* qkv_b   = (const float*)d_in[2];
  const float* q_gamma = (const float*)d_in[3];
  const float* q_beta  = (const float*)d_in[4];
  const float* k_gamma = (const float*)d_in[5];
  const float* k_beta  = (const float*)d_in[6];
  const float* proj_w  = (const float*)d_in[7];
  const float* proj_b  = (const float*)d_in[8];
  float* out = (float*)d_out;

  char* ws = (char*)d_ws;
  bf16_t* x_bf      = (bf16_t*)(ws);               // 12,582,912 B
  bf16_t* wqkv      = (bf16_t*)(ws + 12582912L);   //  3,538,944 B
  bf16_t* wproj     = (bf16_t*)(ws + 16121856L);   //  1,179,648 B
  bf16_t* qkv       = (bf16_t*)(ws + 17301504L);   // 37,748,736 B
  bf16_t* out_heads = (bf16_t*)(ws + 55050240L);   // 12,582,912 B

  cast_all<<<4224, 256, 0, stream>>>(x, x_bf, qkv_w, wqkv, proj_w, wproj);
  gemm_qkv_ln<<<dim3(18, 64), 256, 0, stream>>>(x_bf, wqkv, qkv_b,
                                                q_gamma, q_beta, k_gamma, k_beta,
                                                qkv, 8192, 2304, 768);
  attn_kernel<<<768, 512, 0, stream>>>(qkv, out + 6291456L, out_heads);
  gemm_bt<<<dim3(6, 64), 256, 0, stream>>>(out_heads, wproj, proj_b, out, 8192, 768, 768);
}